// Round 8
// baseline (1026.424 us; speedup 1.0000x reference)
//
#include <hip/hip_runtime.h>
#include <hip/hip_bf16.h>

#define BB 16
#define NN 4096
#define SS 1024
#define KS 32
#define DF 64
#define INC 67
#define C1 64
#define C2 64
#define C3 128
#define ROWS (BB*SS*KS)      /* 524288 */
#define EPSBN 1e-5f
#define F_INF (__builtin_inff())

typedef __bf16 bf16;
typedef __bf16 bfrag __attribute__((ext_vector_type(8)));
typedef float  ffrag __attribute__((ext_vector_type(4)));
typedef float  f2    __attribute__((ext_vector_type(2)));
typedef unsigned long long u64;

// ---- output layout (floats) ----
#define OUT_NXYZ 0
#define OUT_NP   49152
#define OUT_FPS  2146304

// ---- workspace layout (bytes) ----
#define OFF_FPS   0u
#define OFF_NXYZ  65536u
#define OFF_IDX   262144u
#define OFF_STATS 2359296u     /* 3 layers x 64 slots x 256 floats = 196608 B */
#define OFF_ASUM  2555904u
#define OFF_AMAX  2621440u
#define OFF_BNC   2686976u     /* bn3 coeffs: 256 f32 */
#define OFF_SCALE 2690048u
#define OFF_XYZ4  2698240u     /* packed float4 xyz: 16*4096*16B = 1 MB */
#define OFF_YMAX  11086848u    /* 16384*128 f32 */
#define OFF_H1    19475456u    /* 524288*64 bf16 */
#define OFF_H2    86584320u
#define ZERO_BYTES (196608u + 65536u + 65536u)

// u64 max combine via one dpp step (both halves move identically)
#define DPP_MAX_STEP(k, ctrl, rmask, bc) { \
  int _lo = __builtin_amdgcn_update_dpp(0, (int)(unsigned)(k), (ctrl), (rmask), 0xf, (bc)); \
  int _hi = __builtin_amdgcn_update_dpp(0, (int)((k)>>32),     (ctrl), (rmask), 0xf, (bc)); \
  u64 _k2 = ((u64)(unsigned)_hi << 32) | (unsigned)_lo; \
  if (_k2 > (k)) (k) = _k2; }

// f32 max combine via one dpp step (valid when values >= 0: masked lanes inject +0)
#define DPP_FMAX_STEP(v, ctrl, rmask, bc) { \
  int _t = __builtin_amdgcn_update_dpp(0, __float_as_int(v), (ctrl), (rmask), 0xf, (bc)); \
  (v) = fmaxf((v), __uint_as_float((unsigned)_t)); }

// full wave64 max-reduce -> lane 63 holds result (GCN row_shr/row_bcast pattern)
__device__ __forceinline__ u64 dpp_wavemax64(u64 k){
  DPP_MAX_STEP(k, 0x111, 0xf, true)   // row_shr:1
  DPP_MAX_STEP(k, 0x112, 0xf, true)   // row_shr:2
  DPP_MAX_STEP(k, 0x114, 0xf, true)   // row_shr:4
  DPP_MAX_STEP(k, 0x118, 0xf, true)   // row_shr:8
  DPP_MAX_STEP(k, 0x142, 0xa, false)  // row_bcast:15 -> rows 1,3
  DPP_MAX_STEP(k, 0x143, 0xc, false)  // row_bcast:31 -> rows 2,3
  return k;
}

// uniform-lane u64 broadcast via readlane (VALU->SGPR, avoids 2x ds_bpermute)
__device__ __forceinline__ u64 readlane64(u64 k, int lane){
  unsigned lo = (unsigned)__builtin_amdgcn_readlane((int)(unsigned)k, lane);
  unsigned hi = (unsigned)__builtin_amdgcn_readlane((int)(k >> 32),   lane);
  return ((u64)hi << 32) | lo;
}

__device__ __forceinline__ u64 umax64(u64 a, u64 b){ return a > b ? a : b; }

// ================= FPS =========================================================
// Round-2 structure EXACTLY (proven floor: ~570us). Bit-exact vs numpy: no FMA
// contraction, (dx^2+dy^2)+dz^2 order, argmax ties -> lowest index.
// 256 threads / 4 waves / 16 pts/lane; serial argmax chain hidden under dist
// issue. Exchange tail = DPP wavemax + ballot/ctz/readlane + 4-slot LDS tree +
// lc[i] read: irreducibly 2 LDS windows + barrier (r6 evidence: register-payload
// schemes break f2 packing or hit scratch; conservation otherwise). FROZEN.
// Added (free): publishes a packed float4 copy of xyz for knn, overlapped
// before the main loop.
__global__ __launch_bounds__(256) void fps_kernel(const float* __restrict__ xyz,
                                                  int* __restrict__ fps_i,
                                                  float* __restrict__ nxyz_ws,
                                                  float4* __restrict__ xyz4,
                                                  float* __restrict__ out)
{
  #pragma clang fp contract(off)
  __shared__ __align__(16) float4 lc[NN];
  __shared__ int lfps[SS];
  __shared__ __align__(16) u64 slotk[2][4];
  int b = blockIdx.x, t = threadIdx.x;
  const float* xb = xyz + (size_t)b*NN*3;
  for (int p = t; p < NN; p += 256){
    lc[p] = make_float4(xb[p*3], xb[p*3+1], xb[p*3+2], 0.f);
  }
  __syncthreads();
  // publish packed copy for knn (stores drain during the main loop)
  for (int p = t; p < NN; p += 256) xyz4[(size_t)b*NN + p] = lc[p];
  f2 px2[8], py2[8], pz2[8], pd2[8];
  int p0 = t*16;
  #pragma unroll
  for (int j=0;j<8;++j){
    float4 a = lc[p0+2*j], c = lc[p0+2*j+1];
    px2[j] = (f2){a.x, c.x}; py2[j] = (f2){a.y, c.y}; pz2[j] = (f2){a.z, c.z};
    pd2[j] = (f2){F_INF, F_INF};
  }
  float cx = lc[NN/2].x, cy = lc[NN/2].y, cz = lc[NN/2].z;
  if (t==0) lfps[0]=NN/2;
  int wv = t >> 6, lane = t & 63;
  for (int it=1; it<SS; ++it){
    f2 c2x = (f2){cx,cx}, c2y = (f2){cy,cy}, c2z = (f2){cz,cz};
    float bv=-1.f; int bi=p0;
    #pragma unroll
    for (int j=0;j<8;++j){
      f2 dx = px2[j]-c2x, dy = py2[j]-c2y, dz = pz2[j]-c2z;
      f2 d = (dx*dx + dy*dy) + dz*dz;
      f2 nd = (f2){fminf(pd2[j].x, d.x), fminf(pd2[j].y, d.y)};
      pd2[j]=nd;
      if (nd.x > bv){ bv=nd.x; bi=p0+2*j; }
      if (nd.y > bv){ bv=nd.y; bi=p0+2*j+1; }
    }
    // wave max of bv (distances >= 0, so +0 injection from masked lanes is safe)
    float mv = bv;
    DPP_FMAX_STEP(mv, 0x111, 0xf, true)   // row_shr:1
    DPP_FMAX_STEP(mv, 0x112, 0xf, true)   // row_shr:2
    DPP_FMAX_STEP(mv, 0x114, 0xf, true)   // row_shr:4
    DPP_FMAX_STEP(mv, 0x118, 0xf, true)   // row_shr:8
    DPP_FMAX_STEP(mv, 0x142, 0xa, false)  // row_bcast:15 -> rows 1,3
    DPP_FMAX_STEP(mv, 0x143, 0xc, false)  // row_bcast:31 -> rows 2,3
    float wmax = __uint_as_float((unsigned)__builtin_amdgcn_readlane(__float_as_int(mv), 63));
    u64 em = __ballot(bv == wmax);
    int wl = (int)__builtin_ctzll(em);                  // lowest tied lane == lowest index
    int wbi = __builtin_amdgcn_readlane(bi, wl);
    int p = it & 1;
    if (lane == 0)
      slotk[p][wv] = ((u64)__float_as_uint(wmax) << 32) | (unsigned)(~wbi);
    __syncthreads();
    ulonglong2 sA = *(const ulonglong2*)&slotk[p][0];   // LDS same-addr broadcast
    ulonglong2 sB = *(const ulonglong2*)&slotk[p][2];
    u64 k = umax64(umax64(sA.x, sA.y), umax64(sB.x, sB.y));
    int i = ~(unsigned)k;
    float4 cc = lc[i];
    cx = cc.x; cy = cc.y; cz = cc.z;
    if (t==0) lfps[it]=i;
  }
  __syncthreads();
  for (int s=t; s<SS; s+=256){
    int i = lfps[s];
    fps_i[b*SS+s]=i;
    out[OUT_FPS + b*SS + s] = (float)i;
    float4 cc = lc[i];
    int o3 = (b*SS+s)*3;
    out[OUT_NXYZ+o3]=cc.x; out[OUT_NXYZ+o3+1]=cc.y; out[OUT_NXYZ+o3+2]=cc.z;
    nxyz_ws[o3]=cc.x; nxyz_ws[o3+1]=cc.y; nxyz_ws[o3+2]=cc.z;
  }
}

// ================= kNN: 32 smallest dists per (b,s), ties -> lowest index ======
// key = bits(d)<<32 | i  (min, tie -> lowest i); reduce via wave64 DPP max on ~key.
// Reads the packed float4 xyz copy (aligned 16B loads, one per point).
__global__ __launch_bounds__(64) void knn_kernel(const float4* __restrict__ xyz4,
                                                 const float* __restrict__ nxyz,
                                                 int* __restrict__ knn)
{
  __shared__ float ld[NN];
  int lane = threadIdx.x;
  int bs = blockIdx.x;
  int b = bs >> 10;
  const float4* xb4 = xyz4 + (size_t)b*NN;
  float sx=nxyz[bs*3], sy=nxyz[bs*3+1], sz=nxyz[bs*3+2];
  float gv[8]; int gi[8];
  float lv = F_INF; int li = 0;
  #pragma unroll
  for (int g=0; g<8; ++g){
    float bgv = F_INF; int bgi = 0;
    #pragma unroll
    for (int jj=0; jj<8; ++jj){
      int p = (g*8+jj)*64 + lane;
      float4 P = xb4[p];
      float dx=P.x-sx, dy=P.y-sy, dz=P.z-sz;
      float d = dx*dx+dy*dy+dz*dz;
      ld[p] = d;
      if (d < bgv){ bgv=d; bgi=p; }
    }
    gv[g]=bgv; gi[g]=bgi;
    if (bgv < lv){ lv=bgv; li=bgi; }
  }
  int kept = 0;
  for (int it=0; it<KS; ++it){
    u64 mk = ~(((u64)__float_as_uint(lv) << 32) | (unsigned)li);
    mk = dpp_wavemax64(mk);
    mk = readlane64(mk, 63);
    int i = (int)(unsigned)(~mk);     // low 32 bits of key = index
    if (lane==it) kept = i;
    if ((i & 63) == lane){
      int j = i >> 6;
      ld[i] = F_INF;
      int g = j >> 3;
      float bgv=F_INF; int bgi=0;
      for (int jj=0;jj<8;++jj){
        int p = (g*8+jj)*64 + lane;
        float d = ld[p];
        if (d<bgv){bgv=d;bgi=p;}
      }
      #pragma unroll
      for (int q=0;q<8;++q){ if (q==g){ gv[q]=bgv; gi[q]=bgi; } }
      lv=F_INF; li=0;
      #pragma unroll
      for (int q=0;q<8;++q){ if (gv[q]<lv){ lv=gv[q]; li=gi[q]; } }
    }
  }
  if (lane < KS) knn[bs*KS + lane] = kept;
}

// ===== conv1: 512 thr / 128 rows per block; gather + MFMA (K=96) -> h1 + stats ==
__global__ __launch_bounds__(512) void conv1_kernel(const float* __restrict__ xyz,
                                                    const float* __restrict__ points,
                                                    const float* __restrict__ W0,
                                                    const float* __restrict__ b0,
                                                    const float* __restrict__ nxyz,
                                                    const int* __restrict__ knn,
                                                    bf16* __restrict__ h1,
                                                    float* __restrict__ stats)
{
  __shared__ __align__(16) bf16 As[128][104];
  __shared__ __align__(16) bf16 Bs[64][104];
  __shared__ float s1[C1], s2[C1];
  int t = threadIdx.x;
  int Rbase = blockIdx.x * 128;
  if (t < C1){ s1[t]=0.f; s2[t]=0.f; }
  if (t < 256){ // stage B (weights, channel-reordered: feat first, rel at 64..66)
    int o = t >> 2, q = t & 3;
    const float* wr = W0 + o*INC;
    for (int cc = q*24; cc < q*24+24; ++cc){
      float w;
      if (cc < 64) w = wr[3+cc];
      else if (cc < 67) w = wr[cc-64];
      else w = 0.f;
      Bs[o][cc] = (bf16)w;
    }
  }
  { // stage A (gathered activations), r in 0..127
    int r = t >> 2, q = t & 3;
    int R = Rbase + r;
    int bs = R >> 5;
    int bIdx = bs >> 10;
    int nI = knn[R];
    const float* pr = points + ((size_t)(bIdx*NN + nI))*DF + q*16;
    float4 f0 = *(const float4*)(pr);
    float4 f1 = *(const float4*)(pr+4);
    float4 f2v = *(const float4*)(pr+8);
    float4 f3 = *(const float4*)(pr+12);
    bf16* ap = &As[r][q*16];
    ap[0]=(bf16)f0.x; ap[1]=(bf16)f0.y; ap[2]=(bf16)f0.z; ap[3]=(bf16)f0.w;
    ap[4]=(bf16)f1.x; ap[5]=(bf16)f1.y; ap[6]=(bf16)f1.z; ap[7]=(bf16)f1.w;
    ap[8]=(bf16)f2v.x; ap[9]=(bf16)f2v.y; ap[10]=(bf16)f2v.z; ap[11]=(bf16)f2v.w;
    ap[12]=(bf16)f3.x; ap[13]=(bf16)f3.y; ap[14]=(bf16)f3.z; ap[15]=(bf16)f3.w;
    if (q==0){
      const float* xr = xyz + ((size_t)(bIdx*NN + nI))*3;
      const float* nr = nxyz + bs*3;
      As[r][64]=(bf16)(xr[0]-nr[0]);
      As[r][65]=(bf16)(xr[1]-nr[1]);
      As[r][66]=(bf16)(xr[2]-nr[2]);
      for (int cc=67; cc<96; ++cc) As[r][cc]=(bf16)0.f;
    }
  }
  __syncthreads();
  int wv = t >> 6, lane = t & 63;
  int row16 = wv * 16;
  int arow = lane & 15, kgrp = lane >> 4;
  ffrag acc[4] = {};
  #pragma unroll
  for (int kc = 0; kc < 3; ++kc){
    bfrag af = *(const bfrag*)&As[row16 + arow][kc*32 + kgrp*8];
    #pragma unroll
    for (int nt = 0; nt < 4; ++nt){
      bfrag bfv = *(const bfrag*)&Bs[nt*16 + arow][kc*32 + kgrp*8];
      acc[nt] = __builtin_amdgcn_mfma_f32_16x16x32_bf16(af, bfv, acc[nt], 0,0,0);
    }
  }
  #pragma unroll
  for (int nt=0; nt<4; ++nt){
    int c = nt*16 + arow;
    float bias = b0[c];
    float ls1=0.f, ls2=0.f;
    #pragma unroll
    for (int r=0;r<4;++r){
      float y = acc[nt][r] + bias;
      int grow = Rbase + row16 + kgrp*4 + r;
      h1[(size_t)grow*C1 + c] = (bf16)y;
      ls1 += y; ls2 += y*y;
    }
    ls1 += __shfl_xor(ls1, 16); ls1 += __shfl_xor(ls1, 32);
    ls2 += __shfl_xor(ls2, 16); ls2 += __shfl_xor(ls2, 32);
    if (kgrp==0){ atomicAdd(&s1[c], ls1); atomicAdd(&s2[c], ls2); }
  }
  __syncthreads();
  if (t < C1){
    float* gp = stats + (blockIdx.x & 63)*256;
    atomicAdd(&gp[t], s1[t]);
    atomicAdd(&gp[128 + t], s2[t]);
  }
}

// ===== conv2: 512 thr / 128 rows; bnfin0 prologue + bn1+relu, MFMA -> h2 =======
__global__ __launch_bounds__(512) void conv2_kernel(const bf16* __restrict__ h1,
                                                    const float* __restrict__ W1,
                                                    const float* __restrict__ b1,
                                                    const float* __restrict__ stats0,
                                                    const float* __restrict__ g0,
                                                    const float* __restrict__ be0,
                                                    bf16* __restrict__ h2,
                                                    float* __restrict__ stats)
{
  __shared__ __align__(16) bf16 As[128][72];
  __shared__ __align__(16) bf16 Bs[64][72];
  __shared__ float s1[C2], s2[C2];
  __shared__ float sbA[C2], sbB[C2];
  int t = threadIdx.x;
  int Rbase = blockIdx.x * 128;
  if (t < C2){ s1[t]=0.f; s2[t]=0.f; }
  if (t < C2){ // bnfin prologue (same order as the original bnfin_kernel)
    float a1=0.f, a2=0.f;
    for (int q=0;q<64;++q){ a1 += stats0[q*256+t]; a2 += stats0[q*256+128+t]; }
    float inv = 1.f/(float)ROWS;
    float mu = a1*inv; float var = a2*inv - mu*mu;
    float a = g0[t]*rsqrtf(var + EPSBN);
    sbA[t] = a; sbB[t] = be0[t] - mu*a;
  }
  if (t < 256){
    int o = t >> 2, q = t & 3;
    const float* wr = W1 + o*64 + q*16;
    bf16* bp = &Bs[o][q*16];
    #pragma unroll
    for (int v=0; v<4; ++v){
      float4 f = *(const float4*)(wr + v*4);
      bp[v*4+0]=(bf16)f.x; bp[v*4+1]=(bf16)f.y; bp[v*4+2]=(bf16)f.z; bp[v*4+3]=(bf16)f.w;
    }
  }
  __syncthreads();
  {
    int r = t >> 2, q = t & 3;
    int R = Rbase + r;
    const bf16* hr = h1 + (size_t)R*64 + q*16;
    bfrag h0 = *(const bfrag*)hr;
    bfrag h1v = *(const bfrag*)(hr+8);
    #pragma unroll
    for (int j=0;j<8;++j){
      int c=q*16+j;
      As[r][c] = (bf16)fmaxf(fmaf(sbA[c], (float)h0[j], sbB[c]), 0.f);
    }
    #pragma unroll
    for (int j=0;j<8;++j){
      int c=q*16+8+j;
      As[r][c] = (bf16)fmaxf(fmaf(sbA[c], (float)h1v[j], sbB[c]), 0.f);
    }
  }
  __syncthreads();
  int wv = t >> 6, lane = t & 63;
  int row16 = wv * 16;
  int arow = lane & 15, kgrp = lane >> 4;
  ffrag acc[4] = {};
  #pragma unroll
  for (int kc = 0; kc < 2; ++kc){
    bfrag af = *(const bfrag*)&As[row16 + arow][kc*32 + kgrp*8];
    #pragma unroll
    for (int nt = 0; nt < 4; ++nt){
      bfrag bfv = *(const bfrag*)&Bs[nt*16 + arow][kc*32 + kgrp*8];
      acc[nt] = __builtin_amdgcn_mfma_f32_16x16x32_bf16(af, bfv, acc[nt], 0,0,0);
    }
  }
  #pragma unroll
  for (int nt=0; nt<4; ++nt){
    int c = nt*16 + arow;
    float bias = b1[c];
    float ls1=0.f, ls2=0.f;
    #pragma unroll
    for (int r=0;r<4;++r){
      float y = acc[nt][r] + bias;
      int grow = Rbase + row16 + kgrp*4 + r;
      h2[(size_t)grow*C2 + c] = (bf16)y;
      ls1 += y; ls2 += y*y;
    }
    ls1 += __shfl_xor(ls1, 16); ls1 += __shfl_xor(ls1, 32);
    ls2 += __shfl_xor(ls2, 16); ls2 += __shfl_xor(ls2, 32);
    if (kgrp==0){ atomicAdd(&s1[c], ls1); atomicAdd(&s2[c], ls2); }
  }
  __syncthreads();
  if (t < C2){
    float* gp = stats + (blockIdx.x & 63)*256;
    atomicAdd(&gp[t], s1[t]);
    atomicAdd(&gp[128 + t], s2[t]);
  }
}

// ===== conv3: 512 thr / 128 rows; bnfin1 + bn2+relu, MFMA (N=128), maxpool =====
__global__ __launch_bounds__(512) void conv3_kernel(const bf16* __restrict__ h2,
                                                    const float* __restrict__ W2,
                                                    const float* __restrict__ b2,
                                                    const float* __restrict__ stats1,
                                                    const float* __restrict__ g1,
                                                    const float* __restrict__ be1,
                                                    float* __restrict__ ymax,
                                                    float* __restrict__ stats)
{
  __shared__ __align__(16) bf16 As[128][72];
  __shared__ __align__(16) bf16 Bs[128][72];
  __shared__ float s1[C3], s2[C3];
  __shared__ float wmax[8][C3];
  __shared__ float sbA[C2], sbB[C2];
  int t = threadIdx.x;
  int Rbase = blockIdx.x * 128;
  if (t < C3){ s1[t]=0.f; s2[t]=0.f; }
  if (t < C2){ // bnfin prologue
    float a1=0.f, a2=0.f;
    for (int q=0;q<64;++q){ a1 += stats1[q*256+t]; a2 += stats1[q*256+128+t]; }
    float inv = 1.f/(float)ROWS;
    float mu = a1*inv; float var = a2*inv - mu*mu;
    float a = g1[t]*rsqrtf(var + EPSBN);
    sbA[t] = a; sbB[t] = be1[t] - mu*a;
  }
  if (t < 256){
    int o = t >> 1, q = t & 1;
    const float* wr = W2 + o*64 + q*32;
    bf16* bp = &Bs[o][q*32];
    #pragma unroll
    for (int v=0; v<8; ++v){
      float4 f = *(const float4*)(wr + v*4);
      bp[v*4+0]=(bf16)f.x; bp[v*4+1]=(bf16)f.y; bp[v*4+2]=(bf16)f.z; bp[v*4+3]=(bf16)f.w;
    }
  }
  __syncthreads();
  {
    int r = t >> 2, q = t & 3;
    int R = Rbase + r;
    const bf16* hr = h2 + (size_t)R*64 + q*16;
    bfrag h0 = *(const bfrag*)hr;
    bfrag h1v = *(const bfrag*)(hr+8);
    #pragma unroll
    for (int j=0;j<8;++j){
      int c=q*16+j;
      As[r][c] = (bf16)fmaxf(fmaf(sbA[c], (float)h0[j], sbB[c]), 0.f);
    }
    #pragma unroll
    for (int j=0;j<8;++j){
      int c=q*16+8+j;
      As[r][c] = (bf16)fmaxf(fmaf(sbA[c], (float)h1v[j], sbB[c]), 0.f);
    }
  }
  __syncthreads();
  int wv = t >> 6, lane = t & 63;
  int row16 = wv * 16;
  int arow = lane & 15, kgrp = lane >> 4;
  ffrag acc[8] = {};
  #pragma unroll
  for (int kc = 0; kc < 2; ++kc){
    bfrag af = *(const bfrag*)&As[row16 + arow][kc*32 + kgrp*8];
    #pragma unroll
    for (int nt = 0; nt < 8; ++nt){
      bfrag bfv = *(const bfrag*)&Bs[nt*16 + arow][kc*32 + kgrp*8];
      acc[nt] = __builtin_amdgcn_mfma_f32_16x16x32_bf16(af, bfv, acc[nt], 0,0,0);
    }
  }
  #pragma unroll
  for (int nt=0; nt<8; ++nt){
    int c = nt*16 + arow;
    float bias = b2[c];
    float ls1=0.f, ls2=0.f, mm=-F_INF;
    #pragma unroll
    for (int r=0;r<4;++r){
      float y = acc[nt][r] + bias;
      ls1 += y; ls2 += y*y; mm = fmaxf(mm, y);
    }
    ls1 += __shfl_xor(ls1, 16); ls1 += __shfl_xor(ls1, 32);
    ls2 += __shfl_xor(ls2, 16); ls2 += __shfl_xor(ls2, 32);
    mm = fmaxf(mm, __shfl_xor(mm, 16)); mm = fmaxf(mm, __shfl_xor(mm, 32));
    if (kgrp==0){ atomicAdd(&s1[c], ls1); atomicAdd(&s2[c], ls2); wmax[wv][c]=mm; }
  }
  __syncthreads();
  { // 4 output (b,s) groups per block: grp owns waves 2*grp, 2*grp+1 (32 rows)
    int grp = t >> 7;          // 0..3
    int c = t & 127;
    float m = fmaxf(wmax[grp*2][c], wmax[grp*2+1][c]);
    ymax[(size_t)(blockIdx.x*4 + grp)*C3 + c] = m;
  }
  if (t < C3){
    float* gp = stats + (blockIdx.x & 63)*256;
    atomicAdd(&gp[t], s1[t]);
    atomicAdd(&gp[128 + t], s2[t]);
  }
}

// === bnfin2 prologue + avg/max reduction over relu(bn3(ymax)); publishes bnc ===
// (np0 eliminated: finout re-applies the identical f32 ops from ymax+bnc, which
// is bit-identical to the old store/reload of np0.)
__global__ __launch_bounds__(256) void attreduce_kernel(const float* __restrict__ ymax,
                                                        const float* __restrict__ stats2,
                                                        const float* __restrict__ g2,
                                                        const float* __restrict__ be2,
                                                        float* __restrict__ bnc,
                                                        float* __restrict__ asum,
                                                        unsigned* __restrict__ amax)
{
  __shared__ float rs[256], rm[256];
  __shared__ float sbA[C3], sbB[C3];
  int t = threadIdx.x;
  if (t < C3){ // bnfin prologue
    float a1=0.f, a2=0.f;
    for (int q=0;q<64;++q){ a1 += stats2[q*256+t]; a2 += stats2[q*256+128+t]; }
    float inv = 1.f/(float)ROWS;
    float mu = a1*inv; float var = a2*inv - mu*mu;
    float a = g2[t]*rsqrtf(var + EPSBN);
    sbA[t] = a; sbB[t] = be2[t] - mu*a;
    if (blockIdx.x == 0){ bnc[t] = a; bnc[128+t] = sbB[t]; }
  }
  __syncthreads();
  // 512 blocks: 32 per batch, each covering 32 s-values (2 halves of 16 by h)
  int b = blockIdx.x >> 5, sg = blockIdx.x & 31;
  int c = t & 127, h = t >> 7;
  float a = sbA[c], bb = sbB[c];
  size_t base = ((size_t)(b*1024 + sg*32 + h*16))*128 + c;
  float s = 0.f, m = 0.f;
  #pragma unroll 4
  for (int j=0;j<16;++j){
    float v = fmaxf(fmaf(a, ymax[base + (size_t)j*128], bb), 0.f);
    s += v; m = fmaxf(m, v);
  }
  rs[t]=s; rm[t]=m;
  __syncthreads();
  if (t < 128){
    float s2 = rs[t] + rs[t+128];
    float m2 = fmaxf(rm[t], rm[t+128]);
    atomicAdd(&asum[b*128+t], s2);
    atomicMax(&amax[b*128+t], __float_as_uint(m2));
  }
}

// ================= channel attention (tiny) ====================================
__global__ __launch_bounds__(256) void attn_kernel(const float* __restrict__ asum,
                                                   const unsigned* __restrict__ amax,
                                                   const float* __restrict__ aW1,
                                                   const float* __restrict__ aW2,
                                                   float* __restrict__ scale)
{
  __shared__ float avg[16][128], mx[16][128], hA[16][16], hM[16][16];
  int t = threadIdx.x;
  for (int i=t; i<2048; i+=256){
    int b=i>>7, c=i&127;
    avg[b][c]=asum[i]*(1.f/1024.f); mx[b][c]=__uint_as_float(amax[i]);
  }
  __syncthreads();
  {
    int b=t>>4, r=t&15;
    float sa=0.f, sm=0.f;
    for (int c=0;c<128;++c){ float w=aW1[r*128+c]; sa+=w*avg[b][c]; sm+=w*mx[b][c]; }
    hA[b][r]=fmaxf(sa,0.f); hM[b][r]=fmaxf(sm,0.f);
  }
  __syncthreads();
  for (int i=t;i<2048;i+=256){
    int b=i>>7,c=i&127;
    float o=0.f;
    for (int r=0;r<16;++r){ o += aW2[c*16+r]*(hA[b][r]+hM[b][r]); }
    scale[i] = 1.f/(1.f+expf(-o));
  }
}

// ========== final: bn3+relu (from ymax+bnc) * scale -> out =====================
__global__ __launch_bounds__(256) void finout_kernel(const float* __restrict__ ymax,
                                                     const float* __restrict__ bnc,
                                                     const float* __restrict__ scale,
                                                     float* __restrict__ out)
{
  int i = blockIdx.x*256 + threadIdx.x;
  int c = i & 127; int b = i >> 17;
  float v = fmaxf(fmaf(bnc[c], ymax[i], bnc[128+c]), 0.f);
  out[OUT_NP + i] = v * scale[b*128+c];
}

extern "C" void kernel_launch(void* const* d_in, const int* in_sizes, int n_in,
                              void* d_out, int out_size, void* d_ws, size_t ws_size,
                              hipStream_t stream)
{
  const float* xyz    = (const float*)d_in[0];
  const float* points = (const float*)d_in[1];
  const float* W0 = (const float*)d_in[2];
  const float* b0 = (const float*)d_in[3];
  const float* g0 = (const float*)d_in[4];
  const float* be0= (const float*)d_in[5];
  const float* W1 = (const float*)d_in[6];
  const float* b1 = (const float*)d_in[7];
  const float* g1 = (const float*)d_in[8];
  const float* be1= (const float*)d_in[9];
  const float* W2 = (const float*)d_in[10];
  const float* b2 = (const float*)d_in[11];
  const float* g2 = (const float*)d_in[12];
  const float* be2= (const float*)d_in[13];
  const float* aW1= (const float*)d_in[14];
  const float* aW2= (const float*)d_in[15];
  float* out = (float*)d_out;
  char* ws = (char*)d_ws;

  int*      fpsI  = (int*)(ws + OFF_FPS);
  float*    nxyz  = (float*)(ws + OFF_NXYZ);
  int*      knnI  = (int*)(ws + OFF_IDX);
  float*    stats = (float*)(ws + OFF_STATS);
  float*    asum  = (float*)(ws + OFF_ASUM);
  unsigned* amax  = (unsigned*)(ws + OFF_AMAX);
  float*    bnc   = (float*)(ws + OFF_BNC);
  float*    scl   = (float*)(ws + OFF_SCALE);
  float4*   xyz4  = (float4*)(ws + OFF_XYZ4);
  float*    ymax  = (float*)(ws + OFF_YMAX);
  bf16*     h1    = (bf16*)(ws + OFF_H1);
  bf16*     h2    = (bf16*)(ws + OFF_H2);

  hipMemsetAsync(ws + OFF_STATS, 0, ZERO_BYTES, stream);
  fps_kernel<<<BB, 256, 0, stream>>>(xyz, fpsI, nxyz, xyz4, out);
  knn_kernel<<<BB*SS, 64, 0, stream>>>(xyz4, nxyz, knnI);
  conv1_kernel<<<ROWS/128, 512, 0, stream>>>(xyz, points, W0, b0, nxyz, knnI, h1, stats);
  conv2_kernel<<<ROWS/128, 512, 0, stream>>>(h1, W1, b1, stats, g0, be0, h2, stats + 64*256);
  conv3_kernel<<<ROWS/128, 512, 0, stream>>>(h2, W2, b2, stats + 64*256, g1, be1, ymax, stats + 2*64*256);
  attreduce_kernel<<<512, 256, 0, stream>>>(ymax, stats + 2*64*256, g2, be2, bnc, asum, amax);
  attn_kernel<<<1, 256, 0, stream>>>(asum, amax, aW1, aW2, scl);
  finout_kernel<<<(BB*SS*C3)/256, 256, 0, stream>>>(ymax, bnc, scl, out);
}

// Round 9
// 1020.620 us; speedup vs baseline: 1.0057x; 1.0057x over previous
//
#include <hip/hip_runtime.h>
#include <hip/hip_bf16.h>

#define BB 16
#define NN 4096
#define SS 1024
#define KS 32
#define DF 64
#define INC 67
#define C1 64
#define C2 64
#define C3 128
#define ROWS (BB*SS*KS)      /* 524288 */
#define EPSBN 1e-5f
#define F_INF (__builtin_inff())

typedef __bf16 bf16;
typedef __bf16 bfrag __attribute__((ext_vector_type(8)));
typedef float  ffrag __attribute__((ext_vector_type(4)));
typedef float  f2    __attribute__((ext_vector_type(2)));
typedef unsigned long long u64;

// ---- output layout (floats) ----
#define OUT_NXYZ 0
#define OUT_NP   49152
#define OUT_FPS  2146304

// ---- workspace layout (bytes) ----
#define OFF_FPS   0u
#define OFF_NXYZ  65536u
#define OFF_IDX   262144u
#define OFF_STATS 2359296u     /* 3 layers x 64 slots x 256 floats = 196608 B */
#define OFF_ASUM  2555904u
#define OFF_AMAX  2621440u
#define OFF_BNC   2686976u     /* bn3 coeffs: 256 f32 */
#define OFF_SCALE 2690048u
#define OFF_YMAX  11086848u    /* 16384*128 f32 */
#define OFF_H1    19475456u    /* 524288*64 bf16 */
#define OFF_H2    86584320u
#define ZERO_BYTES (196608u + 65536u + 65536u)

// u64 max combine via one dpp step (both halves move identically)
#define DPP_MAX_STEP(k, ctrl, rmask, bc) { \
  int _lo = __builtin_amdgcn_update_dpp(0, (int)(unsigned)(k), (ctrl), (rmask), 0xf, (bc)); \
  int _hi = __builtin_amdgcn_update_dpp(0, (int)((k)>>32),     (ctrl), (rmask), 0xf, (bc)); \
  u64 _k2 = ((u64)(unsigned)_hi << 32) | (unsigned)_lo; \
  if (_k2 > (k)) (k) = _k2; }

// f32 max combine via one dpp step (valid when values >= 0: masked lanes inject +0)
#define DPP_FMAX_STEP(v, ctrl, rmask, bc) { \
  int _t = __builtin_amdgcn_update_dpp(0, __float_as_int(v), (ctrl), (rmask), 0xf, (bc)); \
  (v) = fmaxf((v), __uint_as_float((unsigned)_t)); }

// full wave64 max-reduce -> lane 63 holds result (GCN row_shr/row_bcast pattern)
__device__ __forceinline__ u64 dpp_wavemax64(u64 k){
  DPP_MAX_STEP(k, 0x111, 0xf, true)   // row_shr:1
  DPP_MAX_STEP(k, 0x112, 0xf, true)   // row_shr:2
  DPP_MAX_STEP(k, 0x114, 0xf, true)   // row_shr:4
  DPP_MAX_STEP(k, 0x118, 0xf, true)   // row_shr:8
  DPP_MAX_STEP(k, 0x142, 0xa, false)  // row_bcast:15 -> rows 1,3
  DPP_MAX_STEP(k, 0x143, 0xc, false)  // row_bcast:31 -> rows 2,3
  return k;
}

// uniform-lane u64 broadcast via readlane (VALU->SGPR, avoids 2x ds_bpermute)
__device__ __forceinline__ u64 readlane64(u64 k, int lane){
  unsigned lo = (unsigned)__builtin_amdgcn_readlane((int)(unsigned)k, lane);
  unsigned hi = (unsigned)__builtin_amdgcn_readlane((int)(k >> 32),   lane);
  return ((u64)hi << 32) | lo;
}

__device__ __forceinline__ u64 umax64(u64 a, u64 b){ return a > b ? a : b; }

// ================= FPS =========================================================
// Round-2 structure EXACTLY (proven floor: ~570us). Bit-exact vs numpy: no FMA
// contraction, (dx^2+dy^2)+dz^2 order, argmax ties -> lowest index.
// 256 threads / 4 waves / 16 pts/lane; serial argmax chain hidden under dist
// issue. Exchange tail = DPP wavemax + ballot/ctz/readlane + 4-slot LDS tree +
// lc[i] read: irreducibly 2 LDS windows + barrier. FROZEN — r6 (+260us:
// coord chain-carry broke f2 packing) and r8 (+4us: xyz4 publish store drain)
// both proved any addition to this kernel costs more than it saves elsewhere.
__global__ __launch_bounds__(256) void fps_kernel(const float* __restrict__ xyz,
                                                  int* __restrict__ fps_i,
                                                  float* __restrict__ nxyz_ws,
                                                  float* __restrict__ out)
{
  #pragma clang fp contract(off)
  __shared__ __align__(16) float4 lc[NN];
  __shared__ int lfps[SS];
  __shared__ __align__(16) u64 slotk[2][4];
  int b = blockIdx.x, t = threadIdx.x;
  const float* xb = xyz + (size_t)b*NN*3;
  for (int p = t; p < NN; p += 256){
    lc[p] = make_float4(xb[p*3], xb[p*3+1], xb[p*3+2], 0.f);
  }
  __syncthreads();
  f2 px2[8], py2[8], pz2[8], pd2[8];
  int p0 = t*16;
  #pragma unroll
  for (int j=0;j<8;++j){
    float4 a = lc[p0+2*j], c = lc[p0+2*j+1];
    px2[j] = (f2){a.x, c.x}; py2[j] = (f2){a.y, c.y}; pz2[j] = (f2){a.z, c.z};
    pd2[j] = (f2){F_INF, F_INF};
  }
  float cx = lc[NN/2].x, cy = lc[NN/2].y, cz = lc[NN/2].z;
  if (t==0) lfps[0]=NN/2;
  int wv = t >> 6, lane = t & 63;
  for (int it=1; it<SS; ++it){
    f2 c2x = (f2){cx,cx}, c2y = (f2){cy,cy}, c2z = (f2){cz,cz};
    float bv=-1.f; int bi=p0;
    #pragma unroll
    for (int j=0;j<8;++j){
      f2 dx = px2[j]-c2x, dy = py2[j]-c2y, dz = pz2[j]-c2z;
      f2 d = (dx*dx + dy*dy) + dz*dz;
      f2 nd = (f2){fminf(pd2[j].x, d.x), fminf(pd2[j].y, d.y)};
      pd2[j]=nd;
      if (nd.x > bv){ bv=nd.x; bi=p0+2*j; }
      if (nd.y > bv){ bv=nd.y; bi=p0+2*j+1; }
    }
    // wave max of bv (distances >= 0, so +0 injection from masked lanes is safe)
    float mv = bv;
    DPP_FMAX_STEP(mv, 0x111, 0xf, true)   // row_shr:1
    DPP_FMAX_STEP(mv, 0x112, 0xf, true)   // row_shr:2
    DPP_FMAX_STEP(mv, 0x114, 0xf, true)   // row_shr:4
    DPP_FMAX_STEP(mv, 0x118, 0xf, true)   // row_shr:8
    DPP_FMAX_STEP(mv, 0x142, 0xa, false)  // row_bcast:15 -> rows 1,3
    DPP_FMAX_STEP(mv, 0x143, 0xc, false)  // row_bcast:31 -> rows 2,3
    float wmax = __uint_as_float((unsigned)__builtin_amdgcn_readlane(__float_as_int(mv), 63));
    u64 em = __ballot(bv == wmax);
    int wl = (int)__builtin_ctzll(em);                  // lowest tied lane == lowest index
    int wbi = __builtin_amdgcn_readlane(bi, wl);
    int p = it & 1;
    if (lane == 0)
      slotk[p][wv] = ((u64)__float_as_uint(wmax) << 32) | (unsigned)(~wbi);
    __syncthreads();
    ulonglong2 sA = *(const ulonglong2*)&slotk[p][0];   // LDS same-addr broadcast
    ulonglong2 sB = *(const ulonglong2*)&slotk[p][2];
    u64 k = umax64(umax64(sA.x, sA.y), umax64(sB.x, sB.y));
    int i = ~(unsigned)k;
    float4 cc = lc[i];
    cx = cc.x; cy = cc.y; cz = cc.z;
    if (t==0) lfps[it]=i;
  }
  __syncthreads();
  for (int s=t; s<SS; s+=256){
    int i = lfps[s];
    fps_i[b*SS+s]=i;
    out[OUT_FPS + b*SS + s] = (float)i;
    float4 cc = lc[i];
    int o3 = (b*SS+s)*3;
    out[OUT_NXYZ+o3]=cc.x; out[OUT_NXYZ+o3+1]=cc.y; out[OUT_NXYZ+o3+2]=cc.z;
    nxyz_ws[o3]=cc.x; nxyz_ws[o3+1]=cc.y; nxyz_ws[o3+2]=cc.z;
  }
}

// ================= kNN: 32 smallest dists per (b,s), ties -> lowest index ======
// key = bits(d)<<32 | i  (min, tie -> lowest i); reduce via wave64 DPP max on ~key.
// (round-7 version: strided xyz reads; r8's float4 copy was net-negative)
__global__ __launch_bounds__(64) void knn_kernel(const float* __restrict__ xyz,
                                                 const float* __restrict__ nxyz,
                                                 int* __restrict__ knn)
{
  __shared__ float ld[NN];
  int lane = threadIdx.x;
  int bs = blockIdx.x;
  int b = bs >> 10;
  const float* xb = xyz + (size_t)b*NN*3;
  float sx=nxyz[bs*3], sy=nxyz[bs*3+1], sz=nxyz[bs*3+2];
  float gv[8]; int gi[8];
  float lv = F_INF; int li = 0;
  #pragma unroll
  for (int g=0; g<8; ++g){
    float bgv = F_INF; int bgi = 0;
    #pragma unroll
    for (int jj=0; jj<8; ++jj){
      int p = (g*8+jj)*64 + lane;
      float dx=xb[p*3]-sx, dy=xb[p*3+1]-sy, dz=xb[p*3+2]-sz;
      float d = dx*dx+dy*dy+dz*dz;
      ld[p] = d;
      if (d < bgv){ bgv=d; bgi=p; }
    }
    gv[g]=bgv; gi[g]=bgi;
    if (bgv < lv){ lv=bgv; li=bgi; }
  }
  int kept = 0;
  for (int it=0; it<KS; ++it){
    u64 mk = ~(((u64)__float_as_uint(lv) << 32) | (unsigned)li);
    mk = dpp_wavemax64(mk);
    mk = readlane64(mk, 63);
    int i = (int)(unsigned)(~mk);     // low 32 bits of key = index
    if (lane==it) kept = i;
    if ((i & 63) == lane){
      int j = i >> 6;
      ld[i] = F_INF;
      int g = j >> 3;
      float bgv=F_INF; int bgi=0;
      for (int jj=0;jj<8;++jj){
        int p = (g*8+jj)*64 + lane;
        float d = ld[p];
        if (d<bgv){bgv=d;bgi=p;}
      }
      #pragma unroll
      for (int q=0;q<8;++q){ if (q==g){ gv[q]=bgv; gi[q]=bgi; } }
      lv=F_INF; li=0;
      #pragma unroll
      for (int q=0;q<8;++q){ if (gv[q]<lv){ lv=gv[q]; li=gi[q]; } }
    }
  }
  if (lane < KS) knn[bs*KS + lane] = kept;
}

// ===== conv1: 512 thr / 128 rows per block; gather + MFMA (K=96) -> h1 + stats ==
__global__ __launch_bounds__(512) void conv1_kernel(const float* __restrict__ xyz,
                                                    const float* __restrict__ points,
                                                    const float* __restrict__ W0,
                                                    const float* __restrict__ b0,
                                                    const float* __restrict__ nxyz,
                                                    const int* __restrict__ knn,
                                                    bf16* __restrict__ h1,
                                                    float* __restrict__ stats)
{
  __shared__ __align__(16) bf16 As[128][104];
  __shared__ __align__(16) bf16 Bs[64][104];
  __shared__ float s1[C1], s2[C1];
  int t = threadIdx.x;
  int Rbase = blockIdx.x * 128;
  if (t < C1){ s1[t]=0.f; s2[t]=0.f; }
  if (t < 256){ // stage B (weights, channel-reordered: feat first, rel at 64..66)
    int o = t >> 2, q = t & 3;
    const float* wr = W0 + o*INC;
    for (int cc = q*24; cc < q*24+24; ++cc){
      float w;
      if (cc < 64) w = wr[3+cc];
      else if (cc < 67) w = wr[cc-64];
      else w = 0.f;
      Bs[o][cc] = (bf16)w;
    }
  }
  { // stage A (gathered activations), r in 0..127
    int r = t >> 2, q = t & 3;
    int R = Rbase + r;
    int bs = R >> 5;
    int bIdx = bs >> 10;
    int nI = knn[R];
    const float* pr = points + ((size_t)(bIdx*NN + nI))*DF + q*16;
    float4 f0 = *(const float4*)(pr);
    float4 f1 = *(const float4*)(pr+4);
    float4 f2v = *(const float4*)(pr+8);
    float4 f3 = *(const float4*)(pr+12);
    bf16* ap = &As[r][q*16];
    ap[0]=(bf16)f0.x; ap[1]=(bf16)f0.y; ap[2]=(bf16)f0.z; ap[3]=(bf16)f0.w;
    ap[4]=(bf16)f1.x; ap[5]=(bf16)f1.y; ap[6]=(bf16)f1.z; ap[7]=(bf16)f1.w;
    ap[8]=(bf16)f2v.x; ap[9]=(bf16)f2v.y; ap[10]=(bf16)f2v.z; ap[11]=(bf16)f2v.w;
    ap[12]=(bf16)f3.x; ap[13]=(bf16)f3.y; ap[14]=(bf16)f3.z; ap[15]=(bf16)f3.w;
    if (q==0){
      const float* xr = xyz + ((size_t)(bIdx*NN + nI))*3;
      const float* nr = nxyz + bs*3;
      As[r][64]=(bf16)(xr[0]-nr[0]);
      As[r][65]=(bf16)(xr[1]-nr[1]);
      As[r][66]=(bf16)(xr[2]-nr[2]);
      for (int cc=67; cc<96; ++cc) As[r][cc]=(bf16)0.f;
    }
  }
  __syncthreads();
  int wv = t >> 6, lane = t & 63;
  int row16 = wv * 16;
  int arow = lane & 15, kgrp = lane >> 4;
  ffrag acc[4] = {};
  #pragma unroll
  for (int kc = 0; kc < 3; ++kc){
    bfrag af = *(const bfrag*)&As[row16 + arow][kc*32 + kgrp*8];
    #pragma unroll
    for (int nt = 0; nt < 4; ++nt){
      bfrag bfv = *(const bfrag*)&Bs[nt*16 + arow][kc*32 + kgrp*8];
      acc[nt] = __builtin_amdgcn_mfma_f32_16x16x32_bf16(af, bfv, acc[nt], 0,0,0);
    }
  }
  #pragma unroll
  for (int nt=0; nt<4; ++nt){
    int c = nt*16 + arow;
    float bias = b0[c];
    float ls1=0.f, ls2=0.f;
    #pragma unroll
    for (int r=0;r<4;++r){
      float y = acc[nt][r] + bias;
      int grow = Rbase + row16 + kgrp*4 + r;
      h1[(size_t)grow*C1 + c] = (bf16)y;
      ls1 += y; ls2 += y*y;
    }
    ls1 += __shfl_xor(ls1, 16); ls1 += __shfl_xor(ls1, 32);
    ls2 += __shfl_xor(ls2, 16); ls2 += __shfl_xor(ls2, 32);
    if (kgrp==0){ atomicAdd(&s1[c], ls1); atomicAdd(&s2[c], ls2); }
  }
  __syncthreads();
  if (t < C1){
    float* gp = stats + (blockIdx.x & 63)*256;
    atomicAdd(&gp[t], s1[t]);
    atomicAdd(&gp[128 + t], s2[t]);
  }
}

// ===== conv2: 512 thr / 128 rows; bnfin0 prologue + bn1+relu, MFMA -> h2 =======
__global__ __launch_bounds__(512) void conv2_kernel(const bf16* __restrict__ h1,
                                                    const float* __restrict__ W1,
                                                    const float* __restrict__ b1,
                                                    const float* __restrict__ stats0,
                                                    const float* __restrict__ g0,
                                                    const float* __restrict__ be0,
                                                    bf16* __restrict__ h2,
                                                    float* __restrict__ stats)
{
  __shared__ __align__(16) bf16 As[128][72];
  __shared__ __align__(16) bf16 Bs[64][72];
  __shared__ float s1[C2], s2[C2];
  __shared__ float sbA[C2], sbB[C2];
  int t = threadIdx.x;
  int Rbase = blockIdx.x * 128;
  if (t < C2){ s1[t]=0.f; s2[t]=0.f; }
  if (t < C2){ // bnfin prologue (same order as the original bnfin_kernel)
    float a1=0.f, a2=0.f;
    for (int q=0;q<64;++q){ a1 += stats0[q*256+t]; a2 += stats0[q*256+128+t]; }
    float inv = 1.f/(float)ROWS;
    float mu = a1*inv; float var = a2*inv - mu*mu;
    float a = g0[t]*rsqrtf(var + EPSBN);
    sbA[t] = a; sbB[t] = be0[t] - mu*a;
  }
  if (t < 256){
    int o = t >> 2, q = t & 3;
    const float* wr = W1 + o*64 + q*16;
    bf16* bp = &Bs[o][q*16];
    #pragma unroll
    for (int v=0; v<4; ++v){
      float4 f = *(const float4*)(wr + v*4);
      bp[v*4+0]=(bf16)f.x; bp[v*4+1]=(bf16)f.y; bp[v*4+2]=(bf16)f.z; bp[v*4+3]=(bf16)f.w;
    }
  }
  __syncthreads();
  {
    int r = t >> 2, q = t & 3;
    int R = Rbase + r;
    const bf16* hr = h1 + (size_t)R*64 + q*16;
    bfrag h0 = *(const bfrag*)hr;
    bfrag h1v = *(const bfrag*)(hr+8);
    #pragma unroll
    for (int j=0;j<8;++j){
      int c=q*16+j;
      As[r][c] = (bf16)fmaxf(fmaf(sbA[c], (float)h0[j], sbB[c]), 0.f);
    }
    #pragma unroll
    for (int j=0;j<8;++j){
      int c=q*16+8+j;
      As[r][c] = (bf16)fmaxf(fmaf(sbA[c], (float)h1v[j], sbB[c]), 0.f);
    }
  }
  __syncthreads();
  int wv = t >> 6, lane = t & 63;
  int row16 = wv * 16;
  int arow = lane & 15, kgrp = lane >> 4;
  ffrag acc[4] = {};
  #pragma unroll
  for (int kc = 0; kc < 2; ++kc){
    bfrag af = *(const bfrag*)&As[row16 + arow][kc*32 + kgrp*8];
    #pragma unroll
    for (int nt = 0; nt < 4; ++nt){
      bfrag bfv = *(const bfrag*)&Bs[nt*16 + arow][kc*32 + kgrp*8];
      acc[nt] = __builtin_amdgcn_mfma_f32_16x16x32_bf16(af, bfv, acc[nt], 0,0,0);
    }
  }
  #pragma unroll
  for (int nt=0; nt<4; ++nt){
    int c = nt*16 + arow;
    float bias = b1[c];
    float ls1=0.f, ls2=0.f;
    #pragma unroll
    for (int r=0;r<4;++r){
      float y = acc[nt][r] + bias;
      int grow = Rbase + row16 + kgrp*4 + r;
      h2[(size_t)grow*C2 + c] = (bf16)y;
      ls1 += y; ls2 += y*y;
    }
    ls1 += __shfl_xor(ls1, 16); ls1 += __shfl_xor(ls1, 32);
    ls2 += __shfl_xor(ls2, 16); ls2 += __shfl_xor(ls2, 32);
    if (kgrp==0){ atomicAdd(&s1[c], ls1); atomicAdd(&s2[c], ls2); }
  }
  __syncthreads();
  if (t < C2){
    float* gp = stats + (blockIdx.x & 63)*256;
    atomicAdd(&gp[t], s1[t]);
    atomicAdd(&gp[128 + t], s2[t]);
  }
}

// ===== conv3: 512 thr / 128 rows; bnfin1 + bn2+relu, MFMA (N=128), maxpool =====
__global__ __launch_bounds__(512) void conv3_kernel(const bf16* __restrict__ h2,
                                                    const float* __restrict__ W2,
                                                    const float* __restrict__ b2,
                                                    const float* __restrict__ stats1,
                                                    const float* __restrict__ g1,
                                                    const float* __restrict__ be1,
                                                    float* __restrict__ ymax,
                                                    float* __restrict__ stats)
{
  __shared__ __align__(16) bf16 As[128][72];
  __shared__ __align__(16) bf16 Bs[128][72];
  __shared__ float s1[C3], s2[C3];
  __shared__ float wmax[8][C3];
  __shared__ float sbA[C2], sbB[C2];
  int t = threadIdx.x;
  int Rbase = blockIdx.x * 128;
  if (t < C3){ s1[t]=0.f; s2[t]=0.f; }
  if (t < C2){ // bnfin prologue
    float a1=0.f, a2=0.f;
    for (int q=0;q<64;++q){ a1 += stats1[q*256+t]; a2 += stats1[q*256+128+t]; }
    float inv = 1.f/(float)ROWS;
    float mu = a1*inv; float var = a2*inv - mu*mu;
    float a = g1[t]*rsqrtf(var + EPSBN);
    sbA[t] = a; sbB[t] = be1[t] - mu*a;
  }
  if (t < 256){
    int o = t >> 1, q = t & 1;
    const float* wr = W2 + o*64 + q*32;
    bf16* bp = &Bs[o][q*32];
    #pragma unroll
    for (int v=0; v<8; ++v){
      float4 f = *(const float4*)(wr + v*4);
      bp[v*4+0]=(bf16)f.x; bp[v*4+1]=(bf16)f.y; bp[v*4+2]=(bf16)f.z; bp[v*4+3]=(bf16)f.w;
    }
  }
  __syncthreads();
  {
    int r = t >> 2, q = t & 3;
    int R = Rbase + r;
    const bf16* hr = h2 + (size_t)R*64 + q*16;
    bfrag h0 = *(const bfrag*)hr;
    bfrag h1v = *(const bfrag*)(hr+8);
    #pragma unroll
    for (int j=0;j<8;++j){
      int c=q*16+j;
      As[r][c] = (bf16)fmaxf(fmaf(sbA[c], (float)h0[j], sbB[c]), 0.f);
    }
    #pragma unroll
    for (int j=0;j<8;++j){
      int c=q*16+8+j;
      As[r][c] = (bf16)fmaxf(fmaf(sbA[c], (float)h1v[j], sbB[c]), 0.f);
    }
  }
  __syncthreads();
  int wv = t >> 6, lane = t & 63;
  int row16 = wv * 16;
  int arow = lane & 15, kgrp = lane >> 4;
  ffrag acc[8] = {};
  #pragma unroll
  for (int kc = 0; kc < 2; ++kc){
    bfrag af = *(const bfrag*)&As[row16 + arow][kc*32 + kgrp*8];
    #pragma unroll
    for (int nt = 0; nt < 8; ++nt){
      bfrag bfv = *(const bfrag*)&Bs[nt*16 + arow][kc*32 + kgrp*8];
      acc[nt] = __builtin_amdgcn_mfma_f32_16x16x32_bf16(af, bfv, acc[nt], 0,0,0);
    }
  }
  #pragma unroll
  for (int nt=0; nt<8; ++nt){
    int c = nt*16 + arow;
    float bias = b2[c];
    float ls1=0.f, ls2=0.f, mm=-F_INF;
    #pragma unroll
    for (int r=0;r<4;++r){
      float y = acc[nt][r] + bias;
      ls1 += y; ls2 += y*y; mm = fmaxf(mm, y);
    }
    ls1 += __shfl_xor(ls1, 16); ls1 += __shfl_xor(ls1, 32);
    ls2 += __shfl_xor(ls2, 16); ls2 += __shfl_xor(ls2, 32);
    mm = fmaxf(mm, __shfl_xor(mm, 16)); mm = fmaxf(mm, __shfl_xor(mm, 32));
    if (kgrp==0){ atomicAdd(&s1[c], ls1); atomicAdd(&s2[c], ls2); wmax[wv][c]=mm; }
  }
  __syncthreads();
  { // 4 output (b,s) groups per block: grp owns waves 2*grp, 2*grp+1 (32 rows)
    int grp = t >> 7;          // 0..3
    int c = t & 127;
    float m = fmaxf(wmax[grp*2][c], wmax[grp*2+1][c]);
    ymax[(size_t)(blockIdx.x*4 + grp)*C3 + c] = m;
  }
  if (t < C3){
    float* gp = stats + (blockIdx.x & 63)*256;
    atomicAdd(&gp[t], s1[t]);
    atomicAdd(&gp[128 + t], s2[t]);
  }
}

// === bnfin2 prologue + avg/max reduction over relu(bn3(ymax)); publishes bnc ===
// (np0 eliminated: finout re-applies the identical f32 ops from ymax+bnc, which
// is bit-identical to the old store/reload of np0.)
__global__ __launch_bounds__(256) void attreduce_kernel(const float* __restrict__ ymax,
                                                        const float* __restrict__ stats2,
                                                        const float* __restrict__ g2,
                                                        const float* __restrict__ be2,
                                                        float* __restrict__ bnc,
                                                        float* __restrict__ asum,
                                                        unsigned* __restrict__ amax)
{
  __shared__ float rs[256], rm[256];
  __shared__ float sbA[C3], sbB[C3];
  int t = threadIdx.x;
  if (t < C3){ // bnfin prologue
    float a1=0.f, a2=0.f;
    for (int q=0;q<64;++q){ a1 += stats2[q*256+t]; a2 += stats2[q*256+128+t]; }
    float inv = 1.f/(float)ROWS;
    float mu = a1*inv; float var = a2*inv - mu*mu;
    float a = g2[t]*rsqrtf(var + EPSBN);
    sbA[t] = a; sbB[t] = be2[t] - mu*a;
    if (blockIdx.x == 0){ bnc[t] = a; bnc[128+t] = sbB[t]; }
  }
  __syncthreads();
  // 512 blocks: 32 per batch, each covering 32 s-values (2 halves of 16 by h)
  int b = blockIdx.x >> 5, sg = blockIdx.x & 31;
  int c = t & 127, h = t >> 7;
  float a = sbA[c], bb = sbB[c];
  size_t base = ((size_t)(b*1024 + sg*32 + h*16))*128 + c;
  float s = 0.f, m = 0.f;
  #pragma unroll 4
  for (int j=0;j<16;++j){
    float v = fmaxf(fmaf(a, ymax[base + (size_t)j*128], bb), 0.f);
    s += v; m = fmaxf(m, v);
  }
  rs[t]=s; rm[t]=m;
  __syncthreads();
  if (t < 128){
    float s2 = rs[t] + rs[t+128];
    float m2 = fmaxf(rm[t], rm[t+128]);
    atomicAdd(&asum[b*128+t], s2);
    atomicMax(&amax[b*128+t], __float_as_uint(m2));
  }
}

// ================= channel attention (tiny) ====================================
__global__ __launch_bounds__(256) void attn_kernel(const float* __restrict__ asum,
                                                   const unsigned* __restrict__ amax,
                                                   const float* __restrict__ aW1,
                                                   const float* __restrict__ aW2,
                                                   float* __restrict__ scale)
{
  __shared__ float avg[16][128], mx[16][128], hA[16][16], hM[16][16];
  int t = threadIdx.x;
  for (int i=t; i<2048; i+=256){
    int b=i>>7, c=i&127;
    avg[b][c]=asum[i]*(1.f/1024.f); mx[b][c]=__uint_as_float(amax[i]);
  }
  __syncthreads();
  {
    int b=t>>4, r=t&15;
    float sa=0.f, sm=0.f;
    for (int c=0;c<128;++c){ float w=aW1[r*128+c]; sa+=w*avg[b][c]; sm+=w*mx[b][c]; }
    hA[b][r]=fmaxf(sa,0.f); hM[b][r]=fmaxf(sm,0.f);
  }
  __syncthreads();
  for (int i=t;i<2048;i+=256){
    int b=i>>7,c=i&127;
    float o=0.f;
    for (int r=0;r<16;++r){ o += aW2[c*16+r]*(hA[b][r]+hM[b][r]); }
    scale[i] = 1.f/(1.f+expf(-o));
  }
}

// ========== final: bn3+relu (from ymax+bnc) * scale -> out =====================
__global__ __launch_bounds__(256) void finout_kernel(const float* __restrict__ ymax,
                                                     const float* __restrict__ bnc,
                                                     const float* __restrict__ scale,
                                                     float* __restrict__ out)
{
  int i = blockIdx.x*256 + threadIdx.x;
  int c = i & 127; int b = i >> 17;
  float v = fmaxf(fmaf(bnc[c], ymax[i], bnc[128+c]), 0.f);
  out[OUT_NP + i] = v * scale[b*128+c];
}

extern "C" void kernel_launch(void* const* d_in, const int* in_sizes, int n_in,
                              void* d_out, int out_size, void* d_ws, size_t ws_size,
                              hipStream_t stream)
{
  const float* xyz    = (const float*)d_in[0];
  const float* points = (const float*)d_in[1];
  const float* W0 = (const float*)d_in[2];
  const float* b0 = (const float*)d_in[3];
  const float* g0 = (const float*)d_in[4];
  const float* be0= (const float*)d_in[5];
  const float* W1 = (const float*)d_in[6];
  const float* b1 = (const float*)d_in[7];
  const float* g1 = (const float*)d_in[8];
  const float* be1= (const float*)d_in[9];
  const float* W2 = (const float*)d_in[10];
  const float* b2 = (const float*)d_in[11];
  const float* g2 = (const float*)d_in[12];
  const float* be2= (const float*)d_in[13];
  const float* aW1= (const float*)d_in[14];
  const float* aW2= (const float*)d_in[15];
  float* out = (float*)d_out;
  char* ws = (char*)d_ws;

  int*      fpsI  = (int*)(ws + OFF_FPS);
  float*    nxyz  = (float*)(ws + OFF_NXYZ);
  int*      knnI  = (int*)(ws + OFF_IDX);
  float*    stats = (float*)(ws + OFF_STATS);
  float*    asum  = (float*)(ws + OFF_ASUM);
  unsigned* amax  = (unsigned*)(ws + OFF_AMAX);
  float*    bnc   = (float*)(ws + OFF_BNC);
  float*    scl   = (float*)(ws + OFF_SCALE);
  float*    ymax  = (float*)(ws + OFF_YMAX);
  bf16*     h1    = (bf16*)(ws + OFF_H1);
  bf16*     h2    = (bf16*)(ws + OFF_H2);

  hipMemsetAsync(ws + OFF_STATS, 0, ZERO_BYTES, stream);
  fps_kernel<<<BB, 256, 0, stream>>>(xyz, fpsI, nxyz, out);
  knn_kernel<<<BB*SS, 64, 0, stream>>>(xyz, nxyz, knnI);
  conv1_kernel<<<ROWS/128, 512, 0, stream>>>(xyz, points, W0, b0, nxyz, knnI, h1, stats);
  conv2_kernel<<<ROWS/128, 512, 0, stream>>>(h1, W1, b1, stats, g0, be0, h2, stats + 64*256);
  conv3_kernel<<<ROWS/128, 512, 0, stream>>>(h2, W2, b2, stats + 64*256, g1, be1, ymax, stats + 2*64*256);
  attreduce_kernel<<<512, 256, 0, stream>>>(ymax, stats + 2*64*256, g2, be2, bnc, asum, amax);
  attn_kernel<<<1, 256, 0, stream>>>(asum, amax, aW1, aW2, scl);
  finout_kernel<<<(BB*SS*C3)/256, 256, 0, stream>>>(ymax, bnc, scl, out);
}

// Round 10
// 1016.312 us; speedup vs baseline: 1.0100x; 1.0042x over previous
//
#include <hip/hip_runtime.h>
#include <hip/hip_bf16.h>

#define BB 16
#define NN 4096
#define SS 1024
#define KS 32
#define DF 64
#define INC 67
#define C1 64
#define C2 64
#define C3 128
#define ROWS (BB*SS*KS)      /* 524288 */
#define EPSBN 1e-5f
#define F_INF (__builtin_inff())

typedef __bf16 bf16;
typedef __bf16 bfrag __attribute__((ext_vector_type(8)));
typedef float  ffrag __attribute__((ext_vector_type(4)));
typedef float  f2    __attribute__((ext_vector_type(2)));
typedef unsigned long long u64;

// ---- output layout (floats) ----
#define OUT_NXYZ 0
#define OUT_NP   49152
#define OUT_FPS  2146304

// ---- workspace layout (bytes) ----
#define OFF_FPS   0u
#define OFF_NXYZ  65536u
#define OFF_IDX   262144u
#define OFF_STATS 2359296u     /* 3 layers x 64 slots x 256 floats = 196608 B */
#define OFF_ASUM  2555904u
#define OFF_AMAX  2621440u
#define OFF_BNC   2686976u     /* bn3 coeffs: 256 f32 */
#define OFF_YMAX  11086848u    /* 16384*128 f32 */
#define OFF_H1    19475456u    /* 524288*64 bf16 */
#define OFF_H2    86584320u
#define ZERO_BYTES (196608u + 65536u + 65536u)

// u64 max combine via one dpp step (both halves move identically)
#define DPP_MAX_STEP(k, ctrl, rmask, bc) { \
  int _lo = __builtin_amdgcn_update_dpp(0, (int)(unsigned)(k), (ctrl), (rmask), 0xf, (bc)); \
  int _hi = __builtin_amdgcn_update_dpp(0, (int)((k)>>32),     (ctrl), (rmask), 0xf, (bc)); \
  u64 _k2 = ((u64)(unsigned)_hi << 32) | (unsigned)_lo; \
  if (_k2 > (k)) (k) = _k2; }

// f32 max combine via one dpp step (valid when values >= 0: masked lanes inject +0)
#define DPP_FMAX_STEP(v, ctrl, rmask, bc) { \
  int _t = __builtin_amdgcn_update_dpp(0, __float_as_int(v), (ctrl), (rmask), 0xf, (bc)); \
  (v) = fmaxf((v), __uint_as_float((unsigned)_t)); }

// full wave64 max-reduce -> lane 63 holds result (GCN row_shr/row_bcast pattern)
__device__ __forceinline__ u64 dpp_wavemax64(u64 k){
  DPP_MAX_STEP(k, 0x111, 0xf, true)   // row_shr:1
  DPP_MAX_STEP(k, 0x112, 0xf, true)   // row_shr:2
  DPP_MAX_STEP(k, 0x114, 0xf, true)   // row_shr:4
  DPP_MAX_STEP(k, 0x118, 0xf, true)   // row_shr:8
  DPP_MAX_STEP(k, 0x142, 0xa, false)  // row_bcast:15 -> rows 1,3
  DPP_MAX_STEP(k, 0x143, 0xc, false)  // row_bcast:31 -> rows 2,3
  return k;
}

// uniform-lane u64 broadcast via readlane (VALU->SGPR, avoids 2x ds_bpermute)
__device__ __forceinline__ u64 readlane64(u64 k, int lane){
  unsigned lo = (unsigned)__builtin_amdgcn_readlane((int)(unsigned)k, lane);
  unsigned hi = (unsigned)__builtin_amdgcn_readlane((int)(k >> 32),   lane);
  return ((u64)hi << 32) | lo;
}

__device__ __forceinline__ u64 umax64(u64 a, u64 b){ return a > b ? a : b; }

// ================= FPS =========================================================
// Round-2 structure EXACTLY (proven floor: ~570us). Bit-exact vs numpy: no FMA
// contraction, (dx^2+dy^2)+dz^2 order, argmax ties -> lowest index.
// 256 threads / 4 waves / 16 pts/lane; serial argmax chain hidden under dist
// issue. Exchange tail = DPP wavemax + ballot/ctz/readlane + 4-slot LDS tree +
// lc[i] read: irreducibly 2 LDS windows + barrier. FROZEN — r3 (occupancy),
// r5 (chain-split), r6 (register payload), r8 (store overlap) all confirmed
// conservation: the sequential scan has no remaining overlap or slack.
__global__ __launch_bounds__(256) void fps_kernel(const float* __restrict__ xyz,
                                                  int* __restrict__ fps_i,
                                                  float* __restrict__ nxyz_ws,
                                                  float* __restrict__ out)
{
  #pragma clang fp contract(off)
  __shared__ __align__(16) float4 lc[NN];
  __shared__ int lfps[SS];
  __shared__ __align__(16) u64 slotk[2][4];
  int b = blockIdx.x, t = threadIdx.x;
  const float* xb = xyz + (size_t)b*NN*3;
  for (int p = t; p < NN; p += 256){
    lc[p] = make_float4(xb[p*3], xb[p*3+1], xb[p*3+2], 0.f);
  }
  __syncthreads();
  f2 px2[8], py2[8], pz2[8], pd2[8];
  int p0 = t*16;
  #pragma unroll
  for (int j=0;j<8;++j){
    float4 a = lc[p0+2*j], c = lc[p0+2*j+1];
    px2[j] = (f2){a.x, c.x}; py2[j] = (f2){a.y, c.y}; pz2[j] = (f2){a.z, c.z};
    pd2[j] = (f2){F_INF, F_INF};
  }
  float cx = lc[NN/2].x, cy = lc[NN/2].y, cz = lc[NN/2].z;
  if (t==0) lfps[0]=NN/2;
  int wv = t >> 6, lane = t & 63;
  for (int it=1; it<SS; ++it){
    f2 c2x = (f2){cx,cx}, c2y = (f2){cy,cy}, c2z = (f2){cz,cz};
    float bv=-1.f; int bi=p0;
    #pragma unroll
    for (int j=0;j<8;++j){
      f2 dx = px2[j]-c2x, dy = py2[j]-c2y, dz = pz2[j]-c2z;
      f2 d = (dx*dx + dy*dy) + dz*dz;
      f2 nd = (f2){fminf(pd2[j].x, d.x), fminf(pd2[j].y, d.y)};
      pd2[j]=nd;
      if (nd.x > bv){ bv=nd.x; bi=p0+2*j; }
      if (nd.y > bv){ bv=nd.y; bi=p0+2*j+1; }
    }
    // wave max of bv (distances >= 0, so +0 injection from masked lanes is safe)
    float mv = bv;
    DPP_FMAX_STEP(mv, 0x111, 0xf, true)   // row_shr:1
    DPP_FMAX_STEP(mv, 0x112, 0xf, true)   // row_shr:2
    DPP_FMAX_STEP(mv, 0x114, 0xf, true)   // row_shr:4
    DPP_FMAX_STEP(mv, 0x118, 0xf, true)   // row_shr:8
    DPP_FMAX_STEP(mv, 0x142, 0xa, false)  // row_bcast:15 -> rows 1,3
    DPP_FMAX_STEP(mv, 0x143, 0xc, false)  // row_bcast:31 -> rows 2,3
    float wmax = __uint_as_float((unsigned)__builtin_amdgcn_readlane(__float_as_int(mv), 63));
    u64 em = __ballot(bv == wmax);
    int wl = (int)__builtin_ctzll(em);                  // lowest tied lane == lowest index
    int wbi = __builtin_amdgcn_readlane(bi, wl);
    int p = it & 1;
    if (lane == 0)
      slotk[p][wv] = ((u64)__float_as_uint(wmax) << 32) | (unsigned)(~wbi);
    __syncthreads();
    ulonglong2 sA = *(const ulonglong2*)&slotk[p][0];   // LDS same-addr broadcast
    ulonglong2 sB = *(const ulonglong2*)&slotk[p][2];
    u64 k = umax64(umax64(sA.x, sA.y), umax64(sB.x, sB.y));
    int i = ~(unsigned)k;
    float4 cc = lc[i];
    cx = cc.x; cy = cc.y; cz = cc.z;
    if (t==0) lfps[it]=i;
  }
  __syncthreads();
  for (int s=t; s<SS; s+=256){
    int i = lfps[s];
    fps_i[b*SS+s]=i;
    out[OUT_FPS + b*SS + s] = (float)i;
    float4 cc = lc[i];
    int o3 = (b*SS+s)*3;
    out[OUT_NXYZ+o3]=cc.x; out[OUT_NXYZ+o3+1]=cc.y; out[OUT_NXYZ+o3+2]=cc.z;
    nxyz_ws[o3]=cc.x; nxyz_ws[o3+1]=cc.y; nxyz_ws[o3+2]=cc.z;
  }
}

// ================= kNN: 32 smallest dists per (b,s), ties -> lowest index ======
// key = bits(d)<<32 | i  (min, tie -> lowest i); reduce via wave64 DPP max on ~key.
__global__ __launch_bounds__(64) void knn_kernel(const float* __restrict__ xyz,
                                                 const float* __restrict__ nxyz,
                                                 int* __restrict__ knn)
{
  __shared__ float ld[NN];
  int lane = threadIdx.x;
  int bs = blockIdx.x;
  int b = bs >> 10;
  const float* xb = xyz + (size_t)b*NN*3;
  float sx=nxyz[bs*3], sy=nxyz[bs*3+1], sz=nxyz[bs*3+2];
  float gv[8]; int gi[8];
  float lv = F_INF; int li = 0;
  #pragma unroll
  for (int g=0; g<8; ++g){
    float bgv = F_INF; int bgi = 0;
    #pragma unroll
    for (int jj=0; jj<8; ++jj){
      int p = (g*8+jj)*64 + lane;
      float dx=xb[p*3]-sx, dy=xb[p*3+1]-sy, dz=xb[p*3+2]-sz;
      float d = dx*dx+dy*dy+dz*dz;
      ld[p] = d;
      if (d < bgv){ bgv=d; bgi=p; }
    }
    gv[g]=bgv; gi[g]=bgi;
    if (bgv < lv){ lv=bgv; li=bgi; }
  }
  int kept = 0;
  for (int it=0; it<KS; ++it){
    u64 mk = ~(((u64)__float_as_uint(lv) << 32) | (unsigned)li);
    mk = dpp_wavemax64(mk);
    mk = readlane64(mk, 63);
    int i = (int)(unsigned)(~mk);     // low 32 bits of key = index
    if (lane==it) kept = i;
    if ((i & 63) == lane){
      int j = i >> 6;
      ld[i] = F_INF;
      int g = j >> 3;
      float bgv=F_INF; int bgi=0;
      for (int jj=0;jj<8;++jj){
        int p = (g*8+jj)*64 + lane;
        float d = ld[p];
        if (d<bgv){bgv=d;bgi=p;}
      }
      #pragma unroll
      for (int q=0;q<8;++q){ if (q==g){ gv[q]=bgv; gi[q]=bgi; } }
      lv=F_INF; li=0;
      #pragma unroll
      for (int q=0;q<8;++q){ if (gv[q]<lv){ lv=gv[q]; li=gi[q]; } }
    }
  }
  if (lane < KS) knn[bs*KS + lane] = kept;
}

// ===== conv1: 512 thr / 128 rows per block; gather + MFMA (K=96) -> h1 + stats ==
__global__ __launch_bounds__(512) void conv1_kernel(const float* __restrict__ xyz,
                                                    const float* __restrict__ points,
                                                    const float* __restrict__ W0,
                                                    const float* __restrict__ b0,
                                                    const float* __restrict__ nxyz,
                                                    const int* __restrict__ knn,
                                                    bf16* __restrict__ h1,
                                                    float* __restrict__ stats)
{
  __shared__ __align__(16) bf16 As[128][104];
  __shared__ __align__(16) bf16 Bs[64][104];
  __shared__ float s1[C1], s2[C1];
  int t = threadIdx.x;
  int Rbase = blockIdx.x * 128;
  if (t < C1){ s1[t]=0.f; s2[t]=0.f; }
  if (t < 256){ // stage B (weights, channel-reordered: feat first, rel at 64..66)
    int o = t >> 2, q = t & 3;
    const float* wr = W0 + o*INC;
    for (int cc = q*24; cc < q*24+24; ++cc){
      float w;
      if (cc < 64) w = wr[3+cc];
      else if (cc < 67) w = wr[cc-64];
      else w = 0.f;
      Bs[o][cc] = (bf16)w;
    }
  }
  { // stage A (gathered activations), r in 0..127
    int r = t >> 2, q = t & 3;
    int R = Rbase + r;
    int bs = R >> 5;
    int bIdx = bs >> 10;
    int nI = knn[R];
    const float* pr = points + ((size_t)(bIdx*NN + nI))*DF + q*16;
    float4 f0 = *(const float4*)(pr);
    float4 f1 = *(const float4*)(pr+4);
    float4 f2v = *(const float4*)(pr+8);
    float4 f3 = *(const float4*)(pr+12);
    bf16* ap = &As[r][q*16];
    ap[0]=(bf16)f0.x; ap[1]=(bf16)f0.y; ap[2]=(bf16)f0.z; ap[3]=(bf16)f0.w;
    ap[4]=(bf16)f1.x; ap[5]=(bf16)f1.y; ap[6]=(bf16)f1.z; ap[7]=(bf16)f1.w;
    ap[8]=(bf16)f2v.x; ap[9]=(bf16)f2v.y; ap[10]=(bf16)f2v.z; ap[11]=(bf16)f2v.w;
    ap[12]=(bf16)f3.x; ap[13]=(bf16)f3.y; ap[14]=(bf16)f3.z; ap[15]=(bf16)f3.w;
    if (q==0){
      const float* xr = xyz + ((size_t)(bIdx*NN + nI))*3;
      const float* nr = nxyz + bs*3;
      As[r][64]=(bf16)(xr[0]-nr[0]);
      As[r][65]=(bf16)(xr[1]-nr[1]);
      As[r][66]=(bf16)(xr[2]-nr[2]);
      for (int cc=67; cc<96; ++cc) As[r][cc]=(bf16)0.f;
    }
  }
  __syncthreads();
  int wv = t >> 6, lane = t & 63;
  int row16 = wv * 16;
  int arow = lane & 15, kgrp = lane >> 4;
  ffrag acc[4] = {};
  #pragma unroll
  for (int kc = 0; kc < 3; ++kc){
    bfrag af = *(const bfrag*)&As[row16 + arow][kc*32 + kgrp*8];
    #pragma unroll
    for (int nt = 0; nt < 4; ++nt){
      bfrag bfv = *(const bfrag*)&Bs[nt*16 + arow][kc*32 + kgrp*8];
      acc[nt] = __builtin_amdgcn_mfma_f32_16x16x32_bf16(af, bfv, acc[nt], 0,0,0);
    }
  }
  #pragma unroll
  for (int nt=0; nt<4; ++nt){
    int c = nt*16 + arow;
    float bias = b0[c];
    float ls1=0.f, ls2=0.f;
    #pragma unroll
    for (int r=0;r<4;++r){
      float y = acc[nt][r] + bias;
      int grow = Rbase + row16 + kgrp*4 + r;
      h1[(size_t)grow*C1 + c] = (bf16)y;
      ls1 += y; ls2 += y*y;
    }
    ls1 += __shfl_xor(ls1, 16); ls1 += __shfl_xor(ls1, 32);
    ls2 += __shfl_xor(ls2, 16); ls2 += __shfl_xor(ls2, 32);
    if (kgrp==0){ atomicAdd(&s1[c], ls1); atomicAdd(&s2[c], ls2); }
  }
  __syncthreads();
  if (t < C1){
    float* gp = stats + (blockIdx.x & 63)*256;
    atomicAdd(&gp[t], s1[t]);
    atomicAdd(&gp[128 + t], s2[t]);
  }
}

// ===== conv2: 512 thr / 128 rows; bnfin0 prologue + bn1+relu, MFMA -> h2 =======
__global__ __launch_bounds__(512) void conv2_kernel(const bf16* __restrict__ h1,
                                                    const float* __restrict__ W1,
                                                    const float* __restrict__ b1,
                                                    const float* __restrict__ stats0,
                                                    const float* __restrict__ g0,
                                                    const float* __restrict__ be0,
                                                    bf16* __restrict__ h2,
                                                    float* __restrict__ stats)
{
  __shared__ __align__(16) bf16 As[128][72];
  __shared__ __align__(16) bf16 Bs[64][72];
  __shared__ float s1[C2], s2[C2];
  __shared__ float sbA[C2], sbB[C2];
  int t = threadIdx.x;
  int Rbase = blockIdx.x * 128;
  if (t < C2){ s1[t]=0.f; s2[t]=0.f; }
  if (t < C2){ // bnfin prologue (same order as the original bnfin_kernel)
    float a1=0.f, a2=0.f;
    for (int q=0;q<64;++q){ a1 += stats0[q*256+t]; a2 += stats0[q*256+128+t]; }
    float inv = 1.f/(float)ROWS;
    float mu = a1*inv; float var = a2*inv - mu*mu;
    float a = g0[t]*rsqrtf(var + EPSBN);
    sbA[t] = a; sbB[t] = be0[t] - mu*a;
  }
  if (t < 256){
    int o = t >> 2, q = t & 3;
    const float* wr = W1 + o*64 + q*16;
    bf16* bp = &Bs[o][q*16];
    #pragma unroll
    for (int v=0; v<4; ++v){
      float4 f = *(const float4*)(wr + v*4);
      bp[v*4+0]=(bf16)f.x; bp[v*4+1]=(bf16)f.y; bp[v*4+2]=(bf16)f.z; bp[v*4+3]=(bf16)f.w;
    }
  }
  __syncthreads();
  {
    int r = t >> 2, q = t & 3;
    int R = Rbase + r;
    const bf16* hr = h1 + (size_t)R*64 + q*16;
    bfrag h0 = *(const bfrag*)hr;
    bfrag h1v = *(const bfrag*)(hr+8);
    #pragma unroll
    for (int j=0;j<8;++j){
      int c=q*16+j;
      As[r][c] = (bf16)fmaxf(fmaf(sbA[c], (float)h0[j], sbB[c]), 0.f);
    }
    #pragma unroll
    for (int j=0;j<8;++j){
      int c=q*16+8+j;
      As[r][c] = (bf16)fmaxf(fmaf(sbA[c], (float)h1v[j], sbB[c]), 0.f);
    }
  }
  __syncthreads();
  int wv = t >> 6, lane = t & 63;
  int row16 = wv * 16;
  int arow = lane & 15, kgrp = lane >> 4;
  ffrag acc[4] = {};
  #pragma unroll
  for (int kc = 0; kc < 2; ++kc){
    bfrag af = *(const bfrag*)&As[row16 + arow][kc*32 + kgrp*8];
    #pragma unroll
    for (int nt = 0; nt < 4; ++nt){
      bfrag bfv = *(const bfrag*)&Bs[nt*16 + arow][kc*32 + kgrp*8];
      acc[nt] = __builtin_amdgcn_mfma_f32_16x16x32_bf16(af, bfv, acc[nt], 0,0,0);
    }
  }
  #pragma unroll
  for (int nt=0; nt<4; ++nt){
    int c = nt*16 + arow;
    float bias = b1[c];
    float ls1=0.f, ls2=0.f;
    #pragma unroll
    for (int r=0;r<4;++r){
      float y = acc[nt][r] + bias;
      int grow = Rbase + row16 + kgrp*4 + r;
      h2[(size_t)grow*C2 + c] = (bf16)y;
      ls1 += y; ls2 += y*y;
    }
    ls1 += __shfl_xor(ls1, 16); ls1 += __shfl_xor(ls1, 32);
    ls2 += __shfl_xor(ls2, 16); ls2 += __shfl_xor(ls2, 32);
    if (kgrp==0){ atomicAdd(&s1[c], ls1); atomicAdd(&s2[c], ls2); }
  }
  __syncthreads();
  if (t < C2){
    float* gp = stats + (blockIdx.x & 63)*256;
    atomicAdd(&gp[t], s1[t]);
    atomicAdd(&gp[128 + t], s2[t]);
  }
}

// ===== conv3: 512 thr / 128 rows; bnfin1 + bn2+relu, MFMA (N=128), maxpool =====
__global__ __launch_bounds__(512) void conv3_kernel(const bf16* __restrict__ h2,
                                                    const float* __restrict__ W2,
                                                    const float* __restrict__ b2,
                                                    const float* __restrict__ stats1,
                                                    const float* __restrict__ g1,
                                                    const float* __restrict__ be1,
                                                    float* __restrict__ ymax,
                                                    float* __restrict__ stats)
{
  __shared__ __align__(16) bf16 As[128][72];
  __shared__ __align__(16) bf16 Bs[128][72];
  __shared__ float s1[C3], s2[C3];
  __shared__ float wmax[8][C3];
  __shared__ float sbA[C2], sbB[C2];
  int t = threadIdx.x;
  int Rbase = blockIdx.x * 128;
  if (t < C3){ s1[t]=0.f; s2[t]=0.f; }
  if (t < C2){ // bnfin prologue
    float a1=0.f, a2=0.f;
    for (int q=0;q<64;++q){ a1 += stats1[q*256+t]; a2 += stats1[q*256+128+t]; }
    float inv = 1.f/(float)ROWS;
    float mu = a1*inv; float var = a2*inv - mu*mu;
    float a = g1[t]*rsqrtf(var + EPSBN);
    sbA[t] = a; sbB[t] = be1[t] - mu*a;
  }
  if (t < 256){
    int o = t >> 1, q = t & 1;
    const float* wr = W2 + o*64 + q*32;
    bf16* bp = &Bs[o][q*32];
    #pragma unroll
    for (int v=0; v<8; ++v){
      float4 f = *(const float4*)(wr + v*4);
      bp[v*4+0]=(bf16)f.x; bp[v*4+1]=(bf16)f.y; bp[v*4+2]=(bf16)f.z; bp[v*4+3]=(bf16)f.w;
    }
  }
  __syncthreads();
  {
    int r = t >> 2, q = t & 3;
    int R = Rbase + r;
    const bf16* hr = h2 + (size_t)R*64 + q*16;
    bfrag h0 = *(const bfrag*)hr;
    bfrag h1v = *(const bfrag*)(hr+8);
    #pragma unroll
    for (int j=0;j<8;++j){
      int c=q*16+j;
      As[r][c] = (bf16)fmaxf(fmaf(sbA[c], (float)h0[j], sbB[c]), 0.f);
    }
    #pragma unroll
    for (int j=0;j<8;++j){
      int c=q*16+8+j;
      As[r][c] = (bf16)fmaxf(fmaf(sbA[c], (float)h1v[j], sbB[c]), 0.f);
    }
  }
  __syncthreads();
  int wv = t >> 6, lane = t & 63;
  int row16 = wv * 16;
  int arow = lane & 15, kgrp = lane >> 4;
  ffrag acc[8] = {};
  #pragma unroll
  for (int kc = 0; kc < 2; ++kc){
    bfrag af = *(const bfrag*)&As[row16 + arow][kc*32 + kgrp*8];
    #pragma unroll
    for (int nt = 0; nt < 8; ++nt){
      bfrag bfv = *(const bfrag*)&Bs[nt*16 + arow][kc*32 + kgrp*8];
      acc[nt] = __builtin_amdgcn_mfma_f32_16x16x32_bf16(af, bfv, acc[nt], 0,0,0);
    }
  }
  #pragma unroll
  for (int nt=0; nt<8; ++nt){
    int c = nt*16 + arow;
    float bias = b2[c];
    float ls1=0.f, ls2=0.f, mm=-F_INF;
    #pragma unroll
    for (int r=0;r<4;++r){
      float y = acc[nt][r] + bias;
      ls1 += y; ls2 += y*y; mm = fmaxf(mm, y);
    }
    ls1 += __shfl_xor(ls1, 16); ls1 += __shfl_xor(ls1, 32);
    ls2 += __shfl_xor(ls2, 16); ls2 += __shfl_xor(ls2, 32);
    mm = fmaxf(mm, __shfl_xor(mm, 16)); mm = fmaxf(mm, __shfl_xor(mm, 32));
    if (kgrp==0){ atomicAdd(&s1[c], ls1); atomicAdd(&s2[c], ls2); wmax[wv][c]=mm; }
  }
  __syncthreads();
  { // 4 output (b,s) groups per block: grp owns waves 2*grp, 2*grp+1 (32 rows)
    int grp = t >> 7;          // 0..3
    int c = t & 127;
    float m = fmaxf(wmax[grp*2][c], wmax[grp*2+1][c]);
    ymax[(size_t)(blockIdx.x*4 + grp)*C3 + c] = m;
  }
  if (t < C3){
    float* gp = stats + (blockIdx.x & 63)*256;
    atomicAdd(&gp[t], s1[t]);
    atomicAdd(&gp[128 + t], s2[t]);
  }
}

// === bnfin2 prologue + avg/max reduction over relu(bn3(ymax)); publishes bnc ===
__global__ __launch_bounds__(256) void attreduce_kernel(const float* __restrict__ ymax,
                                                        const float* __restrict__ stats2,
                                                        const float* __restrict__ g2,
                                                        const float* __restrict__ be2,
                                                        float* __restrict__ bnc,
                                                        float* __restrict__ asum,
                                                        unsigned* __restrict__ amax)
{
  __shared__ float rs[256], rm[256];
  __shared__ float sbA[C3], sbB[C3];
  int t = threadIdx.x;
  if (t < C3){ // bnfin prologue
    float a1=0.f, a2=0.f;
    for (int q=0;q<64;++q){ a1 += stats2[q*256+t]; a2 += stats2[q*256+128+t]; }
    float inv = 1.f/(float)ROWS;
    float mu = a1*inv; float var = a2*inv - mu*mu;
    float a = g2[t]*rsqrtf(var + EPSBN);
    sbA[t] = a; sbB[t] = be2[t] - mu*a;
    if (blockIdx.x == 0){ bnc[t] = a; bnc[128+t] = sbB[t]; }
  }
  __syncthreads();
  // 512 blocks: 32 per batch, each covering 32 s-values (2 halves of 16 by h)
  int b = blockIdx.x >> 5, sg = blockIdx.x & 31;
  int c = t & 127, h = t >> 7;
  float a = sbA[c], bb = sbB[c];
  size_t base = ((size_t)(b*1024 + sg*32 + h*16))*128 + c;
  float s = 0.f, m = 0.f;
  #pragma unroll 4
  for (int j=0;j<16;++j){
    float v = fmaxf(fmaf(a, ymax[base + (size_t)j*128], bb), 0.f);
    s += v; m = fmaxf(m, v);
  }
  rs[t]=s; rm[t]=m;
  __syncthreads();
  if (t < 128){
    float s2 = rs[t] + rs[t+128];
    float m2 = fmaxf(rm[t], rm[t+128]);
    atomicAdd(&asum[b*128+t], s2);
    atomicMax(&amax[b*128+t], __float_as_uint(m2));
  }
}

// ==== finout: channel-attention prologue (redundant per block, identical FP
// order to the old attn_kernel -> bit-identical scale) + vectorized
// bn3+relu*scale output. 512 blocks x 256 thr, grid-stride float4.
__global__ __launch_bounds__(256) void finout_kernel(const float* __restrict__ ymax,
                                                     const float* __restrict__ bnc,
                                                     const float* __restrict__ asum,
                                                     const unsigned* __restrict__ amax,
                                                     const float* __restrict__ aW1,
                                                     const float* __restrict__ aW2,
                                                     float* __restrict__ out)
{
  __shared__ __align__(16) float avg[16][128], mx[16][128];
  __shared__ float hA[16][16], hM[16][16];
  __shared__ __align__(16) float scl[16][128];
  int t = threadIdx.x;
  for (int i=t; i<2048; i+=256){
    int b=i>>7, c=i&127;
    avg[b][c]=asum[i]*(1.f/1024.f); mx[b][c]=__uint_as_float(amax[i]);
  }
  __syncthreads();
  {
    int b=t>>4, r=t&15;
    float sa=0.f, sm=0.f;
    for (int c=0;c<128;++c){ float w=aW1[r*128+c]; sa+=w*avg[b][c]; sm+=w*mx[b][c]; }
    hA[b][r]=fmaxf(sa,0.f); hM[b][r]=fmaxf(sm,0.f);
  }
  __syncthreads();
  for (int i=t;i<2048;i+=256){
    int b=i>>7,c=i&127;
    float o=0.f;
    for (int r=0;r<16;++r){ o += aW2[c*16+r]*(hA[b][r]+hM[b][r]); }
    scl[b][c] = 1.f/(1.f+expf(-o));
  }
  __syncthreads();
  const float4* ym4 = (const float4*)ymax;
  const float4* bA4 = (const float4*)bnc;
  const float4* bB4 = (const float4*)(bnc + 128);
  float4* out4 = (float4*)(out + OUT_NP);
  const int nvec = (BB*SS*C3)/4;   // 524288
  for (int v = blockIdx.x*256 + t; v < nvec; v += 512*256){
    int q = v & 31;                 // c0 = 4q
    int b = v >> 15;                // (v*4) >> 17
    float4 y = ym4[v];
    float4 a4 = bA4[q], b4 = bB4[q];
    float4 s4 = *(const float4*)&scl[b][q*4];
    float4 r;
    r.x = fmaxf(fmaf(a4.x, y.x, b4.x), 0.f) * s4.x;
    r.y = fmaxf(fmaf(a4.y, y.y, b4.y), 0.f) * s4.y;
    r.z = fmaxf(fmaf(a4.z, y.z, b4.z), 0.f) * s4.z;
    r.w = fmaxf(fmaf(a4.w, y.w, b4.w), 0.f) * s4.w;
    out4[v] = r;
  }
}

extern "C" void kernel_launch(void* const* d_in, const int* in_sizes, int n_in,
                              void* d_out, int out_size, void* d_ws, size_t ws_size,
                              hipStream_t stream)
{
  const float* xyz    = (const float*)d_in[0];
  const float* points = (const float*)d_in[1];
  const float* W0 = (const float*)d_in[2];
  const float* b0 = (const float*)d_in[3];
  const float* g0 = (const float*)d_in[4];
  const float* be0= (const float*)d_in[5];
  const float* W1 = (const float*)d_in[6];
  const float* b1 = (const float*)d_in[7];
  const float* g1 = (const float*)d_in[8];
  const float* be1= (const float*)d_in[9];
  const float* W2 = (const float*)d_in[10];
  const float* b2 = (const float*)d_in[11];
  const float* g2 = (const float*)d_in[12];
  const float* be2= (const float*)d_in[13];
  const float* aW1= (const float*)d_in[14];
  const float* aW2= (const float*)d_in[15];
  float* out = (float*)d_out;
  char* ws = (char*)d_ws;

  int*      fpsI  = (int*)(ws + OFF_FPS);
  float*    nxyz  = (float*)(ws + OFF_NXYZ);
  int*      knnI  = (int*)(ws + OFF_IDX);
  float*    stats = (float*)(ws + OFF_STATS);
  float*    asum  = (float*)(ws + OFF_ASUM);
  unsigned* amax  = (unsigned*)(ws + OFF_AMAX);
  float*    bnc   = (float*)(ws + OFF_BNC);
  float*    ymax  = (float*)(ws + OFF_YMAX);
  bf16*     h1    = (bf16*)(ws + OFF_H1);
  bf16*     h2    = (bf16*)(ws + OFF_H2);

  hipMemsetAsync(ws + OFF_STATS, 0, ZERO_BYTES, stream);
  fps_kernel<<<BB, 256, 0, stream>>>(xyz, fpsI, nxyz, out);
  knn_kernel<<<BB*SS, 64, 0, stream>>>(xyz, nxyz, knnI);
  conv1_kernel<<<ROWS/128, 512, 0, stream>>>(xyz, points, W0, b0, nxyz, knnI, h1, stats);
  conv2_kernel<<<ROWS/128, 512, 0, stream>>>(h1, W1, b1, stats, g0, be0, h2, stats + 64*256);
  conv3_kernel<<<ROWS/128, 512, 0, stream>>>(h2, W2, b2, stats + 64*256, g1, be1, ymax, stats + 2*64*256);
  attreduce_kernel<<<512, 256, 0, stream>>>(ymax, stats + 2*64*256, g2, be2, bnc, asum, amax);
  finout_kernel<<<512, 256, 0, stream>>>(ymax, bnc, asum, amax, aW1, aW2, out);
}